// Round 6
// baseline (2069.384 us; speedup 1.0000x reference)
//
#include <hip/hip_runtime.h>
#include <hip/hip_bf16.h>
#include <math.h>

#define KIMG 8
#define HH 128
#define WW 128
#define NTOK (HH*WW)
#define DD 768
#define CC 10
#define NITER 5
#define GA 32          // assign blocks per image -> 256 blocks total = 1/CU
#define WVS 4          // waves per assign block

// ---------- wave helpers ----------
__device__ __forceinline__ float rl63(float x){
  return __int_as_float(__builtin_amdgcn_readlane(__float_as_int(x), 63));
}
__device__ __forceinline__ float rfl_f(float x){
  return __int_as_float(__builtin_amdgcn_readfirstlane(__float_as_int(x)));
}
template<int CTRL,int RMASK>
__device__ __forceinline__ float dppadd(float x){
  // compiler-managed DPP (hazard-safe): mov_dpp + add
  int y = __builtin_amdgcn_update_dpp(0, __float_as_int(x), CTRL, RMASK, 0xf, true);
  return x + __int_as_float(y);
}
// full-wave sum; total lands in lane 63
__device__ __forceinline__ float wredsum(float x){
  x = dppadd<0x111,0xf>(x);
  x = dppadd<0x112,0xf>(x);
  x = dppadd<0x114,0xf>(x);
  x = dppadd<0x118,0xf>(x);
  x = dppadd<0x142,0xa>(x);
  x = dppadd<0x143,0xc>(x);
  return x;
}
__device__ __forceinline__ float read_dim_f(const int* p){
  int v = *p;
  if (v > 0 && v < (1<<20)) return (float)v;   // plausible integer
  return __int_as_float(v);                    // else float bits
}
// async HBM -> LDS, 16B per lane; LDS dest = wave-uniform base + lane*16
__device__ __forceinline__ void gl16(const float* g, float* l){
  __builtin_amdgcn_global_load_lds(
      (const __attribute__((address_space(1))) void*)g,
      (__attribute__((address_space(3))) void*)l, 16, 0, 0);
}

union F4 { float4 v; float f[4]; };

// ---------- 1. compact valid token indices (deterministic order) ----------
__global__ __launch_bounds__(256) void compact_kernel(const float* __restrict__ mask,
    int* __restrict__ vidx, int* __restrict__ vcnt){
  int k = blockIdx.x, tid = threadIdx.x;
  __shared__ int s[256];
  const float* mk = mask + (size_t)k*NTOK;
  int base = tid*64, c = 0;
  for (int j=0;j<64;j++) c += (mk[base+j] > 0.f) ? 1 : 0;
  s[tid] = c; __syncthreads();
  for (int st=1; st<256; st<<=1){
    int v = s[tid]; int u = (tid>=st) ? s[tid-st] : 0;
    __syncthreads(); s[tid] = v+u; __syncthreads();
  }
  int off = s[tid] - c;          // exclusive prefix
  if (tid==255) vcnt[k] = s[255];
  int* vk = vidx + (size_t)k*NTOK;
  for (int j=0;j<64;j++){ if (mk[base+j] > 0.f) vk[off++] = base+j; }
}

// ---------- 2. initial centroids = tokens[init_idx] ----------
__global__ __launch_bounds__(256) void init_kernel(const float* __restrict__ feat,
  const float* __restrict__ boxes, const float* __restrict__ Wp, const float* __restrict__ bp,
  const int* __restrict__ iidx, const int* __restrict__ prawh, const int* __restrict__ praww,
  float* __restrict__ cent){
  int k = blockIdx.x, tid = threadIdx.x;
  float top = boxes[k*4+0], lft = boxes[k*4+1], bot = boxes[k*4+2], rgt = boxes[k*4+3];
  float rh = read_dim_f(prawh), rw = read_dim_f(praww);
  float inv_rw = 1.f/(rw-1.f), inv_rh = 1.f/(rh-1.f);
  float xs = (rgt-lft)*(1.f/(float)WW), ys = (bot-top)*(1.f/(float)HH);
  for (int c=0;c<CC;c++){
    int tok = iidx[k*CC+c];
    int h = tok>>7, w = tok&127;
    float xg = fminf(fmaxf(((float)w*xs+lft)*inv_rw,0.f),1.f);
    float yg = fminf(fmaxf(((float)h*ys+top)*inv_rh,0.f),1.f);
    const float* fp = feat + ((size_t)k*NTOK + tok)*DD;
    float* cp = cent + ((size_t)k*CC + c)*DD;
    for (int d=tid; d<DD; d+=256)
      cp[d] = fp[d] + xg*Wp[d] + yg*Wp[DD+d] + bp[d];
  }
}

// ---------- 2b. per-cluster scalars: sA=||c||^2-2bp.c, sW0=-2Wp0.c, sW1=-2Wp1.c ----------
__global__ __launch_bounds__(64) void scalar_kernel(const float* __restrict__ cent,
  const float* __restrict__ Wp, const float* __restrict__ bp, float* __restrict__ scal){
  int c = blockIdx.x, k = blockIdx.y, lane = threadIdx.x;
  const float* cp = cent + ((size_t)k*CC+c)*DD;
  float a0=0.f,a1=0.f,ab=0.f,an=0.f;
  #pragma unroll
  for (int j=0;j<12;j++){
    float cv = cp[j*64+lane];
    a0=fmaf(cv,Wp[j*64+lane],a0);
    a1=fmaf(cv,Wp[DD+j*64+lane],a1);
    ab=fmaf(cv,bp[j*64+lane],ab);
    an=fmaf(cv,cv,an);
  }
  a0=wredsum(a0); a1=wredsum(a1); ab=wredsum(ab); an=wredsum(an);
  if (lane==63){
    float* o = scal + ((size_t)k*CC+c)*4;
    o[0]=fmaf(-2.f,ab,an); o[1]=-2.f*a0; o[2]=-2.f*a1; o[3]=0.f;
  }
}

// ---------- 3. assignment + per-block partial sums (hot) ----------
// Per-wave software pipeline: 2-token tiles DMA-staged HBM->LDS via
// global_load_lds (6 x dwordx4 = 6KB/tile), triple-buffered, counted
// s_waitcnt vmcnt(6) -- NO barriers in the hot loop, prefetch never drained.
// lane owns dims d = 256*j + 4*lane + m; centroids in LDS pre-scaled by -2;
// per-cluster scalars in SGPRs.
__global__ __launch_bounds__(256) void assign_kernel(
    const float* __restrict__ feat, const float* __restrict__ boxes,
    const int* __restrict__ prawh, const int* __restrict__ praww,
    const float* __restrict__ cent, const float* __restrict__ scal,
    const int* __restrict__ vidx, const int* __restrict__ vcnt,
    float* __restrict__ fsums, float* __restrict__ osxg, float* __restrict__ osyg,
    int* __restrict__ ocnt)
{
  int g = blockIdx.x, k = blockIdx.y;
  int tid = threadIdx.x, lane = tid & 63, wv = tid >> 6;
  __shared__ float s_cent[CC*DD];           // -2 * centroids
  __shared__ float s_sums[CC*DD];           // physical p = j*256 + m*64 + lane
  __shared__ float s_buf[WVS][3][2*DD];     // per-wave triple-buffered 2-token tiles
  __shared__ float s_sxg[16], s_syg[16];
  __shared__ int   s_cnt[16];
  const float* ck = cent + (size_t)k*CC*DD;
  for (int x=tid;x<CC*DD;x+=256){ s_cent[x] = -2.f*ck[x]; s_sums[x]=0.f; }
  if (tid<16){ s_sxg[tid]=0.f; s_syg[tid]=0.f; s_cnt[tid]=0; }
  __syncthreads();

  // per-cluster scalars -> SGPRs (wave-uniform)
  float sA[CC], sW0[CC], sW1[CC];
  #pragma unroll
  for (int c=0;c<CC;c++){
    F4 sv; sv.v = *(const float4*)(scal + ((size_t)k*CC+c)*4);
    sA[c]=rfl_f(sv.f[0]); sW0[c]=rfl_f(sv.f[1]); sW1[c]=rfl_f(sv.f[2]);
  }

  float top=rfl_f(boxes[k*4+0]), lft=rfl_f(boxes[k*4+1]);
  float bot=rfl_f(boxes[k*4+2]), rgt=rfl_f(boxes[k*4+3]);
  float rh = read_dim_f(prawh), rw = read_dim_f(praww);
  float inv_rw = 1.f/(rw-1.f), inv_rh = 1.f/(rh-1.f);
  float xs = (rgt-lft)*(1.f/(float)WW), ys = (bot-top)*(1.f/(float)HH);

  int count = vcnt[k];
  int nw = GA*WVS;                          // 128 waves per image
  int wid = g*WVS + wv;
  int cbeg = (int)(((long long)count * wid) / nw);
  int cend = (int)(((long long)count * (wid+1)) / nw);
  int mycnt = cend - cbeg;                  // <= 128
  const int* vk = vidx + (size_t)k*NTOK;
  const float* featk = feat + (size_t)k*NTOK*DD;
  int c1 = count - 1;
  // the wave's token indices, preloaded into two lane-held VGPRs
  int vtA = vk[min(cbeg + lane,      c1)];
  int vtB = vk[min(cbeg + 64 + lane, c1)];
  float* mybuf = &s_buf[wv][0][0];

  auto tok_at = [&](int o)->int{            // o in [0, mycnt); clamped
    o = min(o, mycnt-1);
    return (o < 64) ? __builtin_amdgcn_readlane(vtA, o)
                    : __builtin_amdgcn_readlane(vtB, o-64);
  };
  auto stage = [&](int i){                  // tile i -> slot i%3
    float* dst = mybuf + (i%3)*(2*DD);
    int t0 = tok_at(2*i), t1 = tok_at(2*i+1);
    const float* s0 = featk + (size_t)t0*DD + 4*lane;
    const float* s1 = featk + (size_t)t1*DD + 4*lane;
    gl16(s0,     dst);
    gl16(s0+256, dst+256);
    gl16(s0+512, dst+512);
    gl16(s1,     dst+DD);
    gl16(s1+256, dst+DD+256);
    gl16(s1+512, dst+DD+512);
  };

  int nt = (mycnt + 1) >> 1;                // 2-token tiles
  if (nt > 0){
    stage(0);
    if (nt > 1) stage(1);
    for (int i=0; i<nt; ++i){
      if (i+1 < nt) asm volatile("s_waitcnt vmcnt(6)" ::: "memory");
      else          asm volatile("s_waitcnt vmcnt(0)" ::: "memory");

      const float* bpp = mybuf + (i%3)*(2*DD);
      F4 ta[3], tb[3];
      #pragma unroll
      for (int j=0;j<3;j++){
        ta[j].v = *(const float4*)(bpp + j*256 + 4*lane);
        tb[j].v = *(const float4*)(bpp + DD + j*256 + 4*lane);
      }
      int o0 = 2*i;
      int tk0 = tok_at(o0), tk1 = tok_at(o0+1);
      bool v1 = (o0+1) < mycnt;
      float xg0 = fminf(fmaxf(((float)(tk0&127)*xs+lft)*inv_rw,0.f),1.f);
      float yg0 = fminf(fmaxf(((float)(tk0>>7) *ys+top)*inv_rh,0.f),1.f);
      float xg1 = fminf(fmaxf(((float)(tk1&127)*xs+lft)*inv_rw,0.f),1.f);
      float yg1 = fminf(fmaxf(((float)(tk1>>7) *ys+top)*inv_rh,0.f),1.f);

      float best0=3.4e38f, best1=3.4e38f; int bl0=0, bl1=0;
      #pragma unroll
      for (int c=0;c<CC;c++){
        F4 cs0, cs1, cs2;                   // (-2*cent) slice, shared by both tokens
        const float* cp = s_cent + c*DD + 4*lane;
        cs0.v = *(const float4*)(cp);
        cs1.v = *(const float4*)(cp+256);
        cs2.v = *(const float4*)(cp+512);
        float a0 = 0.f, a1 = 0.f;
        #pragma unroll
        for (int m=0;m<4;m++){
          a0 = fmaf(ta[0].f[m], cs0.f[m], a0);
          a0 = fmaf(ta[1].f[m], cs1.f[m], a0);
          a0 = fmaf(ta[2].f[m], cs2.f[m], a0);
          a1 = fmaf(tb[0].f[m], cs0.f[m], a1);
          a1 = fmaf(tb[1].f[m], cs1.f[m], a1);
          a1 = fmaf(tb[2].f[m], cs2.f[m], a1);
        }
        a0 = wredsum(a0); a1 = wredsum(a1);
        float d0 = rl63(a0), d1 = rl63(a1); // = -2*(t.c), uniform
        float sc0 = fmaf(xg0,sW0[c], fmaf(yg0,sW1[c], sA[c])) + d0;
        float sc1 = fmaf(xg1,sW0[c], fmaf(yg1,sW1[c], sA[c])) + d1;
        if (sc0 < best0){ best0=sc0; bl0=c; }
        if (sc1 < best1){ best1=sc1; bl1=c; }
      }
      int b0 = __builtin_amdgcn_readfirstlane(bl0);
      int b1 = __builtin_amdgcn_readfirstlane(bl1);

      {
        float* sb = s_sums + b0*DD + lane;  // physical p = j*256+m*64+lane
        #pragma unroll
        for (int j=0;j<3;j++)
          #pragma unroll
          for (int m=0;m<4;m++)
            atomicAdd(&sb[j*256 + m*64], ta[j].f[m]);
        if (lane==0){
          atomicAdd(&s_cnt[b0],1); atomicAdd(&s_sxg[b0],xg0); atomicAdd(&s_syg[b0],yg0);
        }
      }
      if (v1){
        float* sb = s_sums + b1*DD + lane;
        #pragma unroll
        for (int j=0;j<3;j++)
          #pragma unroll
          for (int m=0;m<4;m++)
            atomicAdd(&sb[j*256 + m*64], tb[j].f[m]);
        if (lane==0){
          atomicAdd(&s_cnt[b1],1); atomicAdd(&s_sxg[b1],xg1); atomicAdd(&s_syg[b1],yg1);
        }
      }
      if (i+2 < nt) stage(i+2);
    }
  }
  __syncthreads();

  float* fo = fsums + ((size_t)(k*GA+g))*CC*DD;
  for (int x=tid;x<CC*DD;x+=256) fo[x]=s_sums[x];
  if (tid<CC){
    size_t o = (size_t)(k*GA+g)*CC + tid;
    osxg[o]=s_sxg[tid]; osyg[o]=s_syg[tid]; ocnt[o]=s_cnt[tid];
  }
}

// ---------- 4. deterministic reduce over GA partials + centroid update ----------
// fsums physical p = j*256 + m*64 + l ; logical d = 256*j + 4*l + m
__global__ __launch_bounds__(256) void update_kernel(
  const float* __restrict__ fsums, const float* __restrict__ osxg, const float* __restrict__ osyg,
  const int* __restrict__ ocnt, const float* __restrict__ Wp, const float* __restrict__ bp,
  float* __restrict__ cent)
{
  int idx = blockIdx.x*256 + threadIdx.x;   // over K*C*D ; (k,c) uniform per block
  int d  = idx % DD;
  int kc = idx / DD;
  int k  = kc / CC, c = kc % CC;
  int j = d >> 8, r = d & 255, l = r >> 2, m = r & 3;
  int p = (j << 8) | (m << 6) | l;
  __shared__ float sX[GA], sY[GA]; __shared__ int sN[GA];
  if (threadIdx.x < GA){
    int g = threadIdx.x;
    size_t o = (size_t)(k*GA+g)*CC + c;
    sX[g]=osxg[o]; sY[g]=osyg[o]; sN[g]=ocnt[o];
  }
  __syncthreads();
  int n=0; float sx=0.f, sy=0.f;
  for (int t=0;t<GA;t++){ n+=sN[t]; sx+=sX[t]; sy+=sY[t]; }
  float s=0.f;
  for (int g=0; g<GA; g++)
    s += fsums[((size_t)(k*GA+g)*CC + c)*DD + p];
  if (n > 0){
    float nf = (float)n;
    float ts = s + sx*Wp[d] + sy*Wp[DD+d] + nf*bp[d];  // factored posenc re-applied
    cent[(size_t)kc*DD + d] = ts / nf;
  } // else keep old centroid
}

// ---------- 5. MLP ----------
__global__ __launch_bounds__(256) void mlp1_kernel(const float* __restrict__ cent,
  const float* __restrict__ W1, const float* __restrict__ b1, float* __restrict__ h1)
{
  int k = blockIdx.y; int col = blockIdx.x*256 + threadIdx.x;
  __shared__ float srow[CC*DD];
  for (int x=threadIdx.x; x<CC*DD; x+=256) srow[x] = cent[(size_t)k*CC*DD + x];
  __syncthreads();
  float acc[CC];
  #pragma unroll
  for (int r=0;r<CC;r++) acc[r]=0.f;
  for (int dd=0; dd<DD; dd++){
    float wv = W1[(size_t)dd*DD + col];
    #pragma unroll
    for (int r=0;r<CC;r++) acc[r] = fmaf(srow[r*DD+dd], wv, acc[r]);
  }
  float bb = b1[col];
  #pragma unroll
  for (int r=0;r<CC;r++){
    float x = acc[r] + bb;
    h1[((size_t)k*CC+r)*DD + col] = 0.5f*x*(1.f+erff(x*0.70710678118654752440f));
  }
}

__global__ __launch_bounds__(256) void mlp2_kernel(const float* __restrict__ h1,
  const float* __restrict__ W2, const float* __restrict__ b2, float* __restrict__ out)
{
  int k = blockIdx.y; int col = blockIdx.x*256 + threadIdx.x;
  __shared__ float srow[CC*DD];
  for (int x=threadIdx.x; x<CC*DD; x+=256) srow[x] = h1[(size_t)k*CC*DD + x];
  __syncthreads();
  float acc[CC];
  #pragma unroll
  for (int r=0;r<CC;r++) acc[r]=0.f;
  for (int dd=0; dd<DD; dd++){
    float wv = W2[(size_t)dd*DD + col];
    #pragma unroll
    for (int r=0;r<CC;r++) acc[r] = fmaf(srow[r*DD+dd], wv, acc[r]);
  }
  float bb2 = b2[col];
  #pragma unroll
  for (int r=0;r<CC;r++) out[((size_t)k*CC+r)*DD + col] = acc[r] + bb2;
}

// ---------- launch ----------
extern "C" void kernel_launch(void* const* d_in, const int* in_sizes, int n_in,
                              void* d_out, int out_size, void* d_ws, size_t ws_size,
                              hipStream_t stream)
{
  const float* feat = (const float*)d_in[0];
  const float* mask = (const float*)d_in[1];
  const float* boxes= (const float*)d_in[2];
  const float* Wp   = (const float*)d_in[3];
  const float* bp   = (const float*)d_in[4];
  const float* W1   = (const float*)d_in[5];
  const float* b1   = (const float*)d_in[6];
  const float* W2   = (const float*)d_in[7];
  const float* b2   = (const float*)d_in[8];
  const int*   iidx = (const int*)d_in[9];
  const int*   prawh= (const int*)d_in[10];
  const int*   praww= (const int*)d_in[11];
  float* out = (float*)d_out;

  auto align = [](size_t x){ return (x + 255) & ~(size_t)255; };
  size_t off = 0;
  size_t o_cent = off; off = align(off + (size_t)KIMG*CC*DD*4);
  size_t o_vidx = off; off = align(off + (size_t)KIMG*NTOK*4);
  size_t o_vcnt = off; off = align(off + (size_t)KIMG*4);
  size_t o_scal = off; off = align(off + (size_t)KIMG*CC*4*4);
  size_t o_h1   = off; off = align(off + (size_t)KIMG*CC*DD*4);
  size_t o_fs   = off; off = align(off + (size_t)KIMG*GA*CC*DD*4);
  size_t o_sx   = off; off = align(off + (size_t)KIMG*GA*CC*4);
  size_t o_sy   = off; off = align(off + (size_t)KIMG*GA*CC*4);
  size_t o_cn   = off; off = align(off + (size_t)KIMG*GA*CC*4);
  (void)ws_size;  // ~10.3 MB needed; prior rounds confirm ws_size >= 16.8 MB

  char* ws = (char*)d_ws;
  float* cent  = (float*)(ws + o_cent);
  int*   vidx  = (int*)  (ws + o_vidx);
  int*   vcnt  = (int*)  (ws + o_vcnt);
  float* scal  = (float*)(ws + o_scal);
  float* h1    = (float*)(ws + o_h1);
  float* fsums = (float*)(ws + o_fs);
  float* sxg   = (float*)(ws + o_sx);
  float* syg   = (float*)(ws + o_sy);
  int*   ocnt  = (int*)  (ws + o_cn);

  compact_kernel<<<KIMG,256,0,stream>>>(mask, vidx, vcnt);
  init_kernel<<<KIMG,256,0,stream>>>(feat, boxes, Wp, bp, iidx, prawh, praww, cent);
  scalar_kernel<<<dim3(CC,KIMG),64,0,stream>>>(cent, Wp, bp, scal);
  for (int it=0; it<NITER; ++it){
    assign_kernel<<<dim3(GA,KIMG),256,0,stream>>>(feat, boxes, prawh, praww,
        cent, scal, vidx, vcnt, fsums, sxg, syg, ocnt);
    update_kernel<<<(KIMG*CC*DD)/256,256,0,stream>>>(fsums, sxg, syg, ocnt, Wp, bp, cent);
    if (it < NITER-1)
      scalar_kernel<<<dim3(CC,KIMG),64,0,stream>>>(cent, Wp, bp, scal);
  }
  mlp1_kernel<<<dim3(3,KIMG),256,0,stream>>>(cent, W1, b1, h1);
  mlp2_kernel<<<dim3(3,KIMG),256,0,stream>>>(h1, W2, b2, out);
}

// Round 7
// 2066.567 us; speedup vs baseline: 1.0014x; 1.0014x over previous
//
#include <hip/hip_runtime.h>
#include <hip/hip_bf16.h>
#include <math.h>

#define KIMG 8
#define HH 128
#define WW 128
#define NTOK (HH*WW)
#define DD 768
#define CC 10
#define NITER 5
#define GA 32          // assign blocks per image -> 256 blocks total = 1/CU
#define WVS 4          // waves per assign block

// ---------- wave helpers ----------
__device__ __forceinline__ float rl63(float x){
  return __int_as_float(__builtin_amdgcn_readlane(__float_as_int(x), 63));
}
__device__ __forceinline__ float rfl_f(float x){
  return __int_as_float(__builtin_amdgcn_readfirstlane(__float_as_int(x)));
}
template<int CTRL,int RMASK>
__device__ __forceinline__ float dppadd(float x){
  // compiler-managed DPP (hazard-safe): mov_dpp + add
  int y = __builtin_amdgcn_update_dpp(0, __float_as_int(x), CTRL, RMASK, 0xf, true);
  return x + __int_as_float(y);
}
// full-wave sum; total lands in lane 63
__device__ __forceinline__ float wredsum(float x){
  x = dppadd<0x111,0xf>(x);
  x = dppadd<0x112,0xf>(x);
  x = dppadd<0x114,0xf>(x);
  x = dppadd<0x118,0xf>(x);
  x = dppadd<0x142,0xa>(x);
  x = dppadd<0x143,0xc>(x);
  return x;
}
__device__ __forceinline__ float read_dim_f(const int* p){
  int v = *p;
  if (v > 0 && v < (1<<20)) return (float)v;   // plausible integer
  return __int_as_float(v);                    // else float bits
}
// async HBM -> LDS, 16B per lane; LDS dest = wave-uniform base + lane*16
__device__ __forceinline__ void gl16(const float* g, float* l){
  __builtin_amdgcn_global_load_lds(
      (const __attribute__((address_space(1))) void*)g,
      (__attribute__((address_space(3))) void*)l, 16, 0, 0);
}

union F4 { float4 v; float f[4]; };

// ---------- 1. compact valid token indices (deterministic order) ----------
__global__ __launch_bounds__(256) void compact_kernel(const float* __restrict__ mask,
    int* __restrict__ vidx, int* __restrict__ vcnt){
  int k = blockIdx.x, tid = threadIdx.x;
  __shared__ int s[256];
  const float* mk = mask + (size_t)k*NTOK;
  int base = tid*64, c = 0;
  for (int j=0;j<64;j++) c += (mk[base+j] > 0.f) ? 1 : 0;
  s[tid] = c; __syncthreads();
  for (int st=1; st<256; st<<=1){
    int v = s[tid]; int u = (tid>=st) ? s[tid-st] : 0;
    __syncthreads(); s[tid] = v+u; __syncthreads();
  }
  int off = s[tid] - c;          // exclusive prefix
  if (tid==255) vcnt[k] = s[255];
  int* vk = vidx + (size_t)k*NTOK;
  for (int j=0;j<64;j++){ if (mk[base+j] > 0.f) vk[off++] = base+j; }
}

// ---------- 2. initial centroids = tokens[init_idx] ----------
__global__ __launch_bounds__(256) void init_kernel(const float* __restrict__ feat,
  const float* __restrict__ boxes, const float* __restrict__ Wp, const float* __restrict__ bp,
  const int* __restrict__ iidx, const int* __restrict__ prawh, const int* __restrict__ praww,
  float* __restrict__ cent){
  int k = blockIdx.x, tid = threadIdx.x;
  float top = boxes[k*4+0], lft = boxes[k*4+1], bot = boxes[k*4+2], rgt = boxes[k*4+3];
  float rh = read_dim_f(prawh), rw = read_dim_f(praww);
  float inv_rw = 1.f/(rw-1.f), inv_rh = 1.f/(rh-1.f);
  float xs = (rgt-lft)*(1.f/(float)WW), ys = (bot-top)*(1.f/(float)HH);
  for (int c=0;c<CC;c++){
    int tok = iidx[k*CC+c];
    int h = tok>>7, w = tok&127;
    float xg = fminf(fmaxf(((float)w*xs+lft)*inv_rw,0.f),1.f);
    float yg = fminf(fmaxf(((float)h*ys+top)*inv_rh,0.f),1.f);
    const float* fp = feat + ((size_t)k*NTOK + tok)*DD;
    float* cp = cent + ((size_t)k*CC + c)*DD;
    for (int d=tid; d<DD; d+=256)
      cp[d] = fp[d] + xg*Wp[d] + yg*Wp[DD+d] + bp[d];
  }
}

// ---------- 2b. per-cluster scalars: sA=||c||^2-2bp.c, sW0=-2Wp0.c, sW1=-2Wp1.c ----------
__global__ __launch_bounds__(64) void scalar_kernel(const float* __restrict__ cent,
  const float* __restrict__ Wp, const float* __restrict__ bp, float* __restrict__ scal){
  int c = blockIdx.x, k = blockIdx.y, lane = threadIdx.x;
  const float* cp = cent + ((size_t)k*CC+c)*DD;
  float a0=0.f,a1=0.f,ab=0.f,an=0.f;
  #pragma unroll
  for (int j=0;j<12;j++){
    float cv = cp[j*64+lane];
    a0=fmaf(cv,Wp[j*64+lane],a0);
    a1=fmaf(cv,Wp[DD+j*64+lane],a1);
    ab=fmaf(cv,bp[j*64+lane],ab);
    an=fmaf(cv,cv,an);
  }
  a0=wredsum(a0); a1=wredsum(a1); ab=wredsum(ab); an=wredsum(an);
  if (lane==63){
    float* o = scal + ((size_t)k*CC+c)*4;
    o[0]=fmaf(-2.f,ab,an); o[1]=-2.f*a0; o[2]=-2.f*a1; o[3]=0.f;
  }
}

// ---------- 3. assignment + per-block partial sums (hot) ----------
// Per-wave software pipeline: 2-token tiles DMA-staged HBM->LDS via
// global_load_lds (6 x dwordx4 = 6KB/tile), triple-buffered, counted
// s_waitcnt vmcnt(6) -- NO barriers in the hot loop, prefetch never drained.
// lane owns dims d = 256*j + 4*lane + m; centroids in LDS pre-scaled by -2;
// per-cluster scalars in SGPRs.
__global__ __launch_bounds__(256) void assign_kernel(
    const float* __restrict__ feat, const float* __restrict__ boxes,
    const int* __restrict__ prawh, const int* __restrict__ praww,
    const float* __restrict__ cent, const float* __restrict__ scal,
    const int* __restrict__ vidx, const int* __restrict__ vcnt,
    float* __restrict__ fsums, float* __restrict__ osxg, float* __restrict__ osyg,
    int* __restrict__ ocnt)
{
  int g = blockIdx.x, k = blockIdx.y;
  int tid = threadIdx.x, lane = tid & 63, wv = tid >> 6;
  __shared__ float s_cent[CC*DD];           // -2 * centroids
  __shared__ float s_sums[CC*DD];           // physical p = j*256 + m*64 + lane
  __shared__ float s_buf[WVS][3][2*DD];     // per-wave triple-buffered 2-token tiles
  __shared__ float s_sxg[16], s_syg[16];
  __shared__ int   s_cnt[16];
  const float* ck = cent + (size_t)k*CC*DD;
  for (int x=tid;x<CC*DD;x+=256){ s_cent[x] = -2.f*ck[x]; s_sums[x]=0.f; }
  if (tid<16){ s_sxg[tid]=0.f; s_syg[tid]=0.f; s_cnt[tid]=0; }
  __syncthreads();

  // per-cluster scalars -> SGPRs (wave-uniform)
  float sA[CC], sW0[CC], sW1[CC];
  #pragma unroll
  for (int c=0;c<CC;c++){
    F4 sv; sv.v = *(const float4*)(scal + ((size_t)k*CC+c)*4);
    sA[c]=rfl_f(sv.f[0]); sW0[c]=rfl_f(sv.f[1]); sW1[c]=rfl_f(sv.f[2]);
  }

  float top=rfl_f(boxes[k*4+0]), lft=rfl_f(boxes[k*4+1]);
  float bot=rfl_f(boxes[k*4+2]), rgt=rfl_f(boxes[k*4+3]);
  float rh = read_dim_f(prawh), rw = read_dim_f(praww);
  float inv_rw = 1.f/(rw-1.f), inv_rh = 1.f/(rh-1.f);
  float xs = (rgt-lft)*(1.f/(float)WW), ys = (bot-top)*(1.f/(float)HH);

  int count = vcnt[k];
  int nw = GA*WVS;                          // 128 waves per image
  int wid = g*WVS + wv;
  int cbeg = (int)(((long long)count * wid) / nw);
  int cend = (int)(((long long)count * (wid+1)) / nw);
  int mycnt = cend - cbeg;                  // <= 128
  const int* vk = vidx + (size_t)k*NTOK;
  const float* featk = feat + (size_t)k*NTOK*DD;
  int c1 = count - 1;
  // the wave's token indices, preloaded into two lane-held VGPRs
  int vtA = vk[min(cbeg + lane,      c1)];
  int vtB = vk[min(cbeg + 64 + lane, c1)];
  float* mybuf = &s_buf[wv][0][0];

  auto tok_at = [&](int o)->int{            // o in [0, mycnt); clamped
    o = min(o, mycnt-1);
    return (o < 64) ? __builtin_amdgcn_readlane(vtA, o)
                    : __builtin_amdgcn_readlane(vtB, o-64);
  };
  auto stage = [&](int i){                  // tile i -> slot i%3
    float* dst = mybuf + (i%3)*(2*DD);
    int t0 = tok_at(2*i), t1 = tok_at(2*i+1);
    const float* s0 = featk + (size_t)t0*DD + 4*lane;
    const float* s1 = featk + (size_t)t1*DD + 4*lane;
    gl16(s0,     dst);
    gl16(s0+256, dst+256);
    gl16(s0+512, dst+512);
    gl16(s1,     dst+DD);
    gl16(s1+256, dst+DD+256);
    gl16(s1+512, dst+DD+512);
  };

  int nt = (mycnt + 1) >> 1;                // 2-token tiles
  if (nt > 0){
    stage(0);
    if (nt > 1) stage(1);
    for (int i=0; i<nt; ++i){
      if (i+1 < nt) asm volatile("s_waitcnt vmcnt(6)" ::: "memory");
      else          asm volatile("s_waitcnt vmcnt(0)" ::: "memory");

      const float* bpp = mybuf + (i%3)*(2*DD);
      F4 ta[3], tb[3];
      #pragma unroll
      for (int j=0;j<3;j++){
        ta[j].v = *(const float4*)(bpp + j*256 + 4*lane);
        tb[j].v = *(const float4*)(bpp + DD + j*256 + 4*lane);
      }
      int o0 = 2*i;
      int tk0 = tok_at(o0), tk1 = tok_at(o0+1);
      bool v1 = (o0+1) < mycnt;
      float xg0 = fminf(fmaxf(((float)(tk0&127)*xs+lft)*inv_rw,0.f),1.f);
      float yg0 = fminf(fmaxf(((float)(tk0>>7) *ys+top)*inv_rh,0.f),1.f);
      float xg1 = fminf(fmaxf(((float)(tk1&127)*xs+lft)*inv_rw,0.f),1.f);
      float yg1 = fminf(fmaxf(((float)(tk1>>7) *ys+top)*inv_rh,0.f),1.f);

      float best0=3.4e38f, best1=3.4e38f; int bl0=0, bl1=0;
      #pragma unroll
      for (int c=0;c<CC;c++){
        F4 cs0, cs1, cs2;                   // (-2*cent) slice, shared by both tokens
        const float* cp = s_cent + c*DD + 4*lane;
        cs0.v = *(const float4*)(cp);
        cs1.v = *(const float4*)(cp+256);
        cs2.v = *(const float4*)(cp+512);
        float a0 = 0.f, a1 = 0.f;
        #pragma unroll
        for (int m=0;m<4;m++){
          a0 = fmaf(ta[0].f[m], cs0.f[m], a0);
          a0 = fmaf(ta[1].f[m], cs1.f[m], a0);
          a0 = fmaf(ta[2].f[m], cs2.f[m], a0);
          a1 = fmaf(tb[0].f[m], cs0.f[m], a1);
          a1 = fmaf(tb[1].f[m], cs1.f[m], a1);
          a1 = fmaf(tb[2].f[m], cs2.f[m], a1);
        }
        a0 = wredsum(a0); a1 = wredsum(a1);
        float d0 = rl63(a0), d1 = rl63(a1); // = -2*(t.c), uniform
        float sc0 = fmaf(xg0,sW0[c], fmaf(yg0,sW1[c], sA[c])) + d0;
        float sc1 = fmaf(xg1,sW0[c], fmaf(yg1,sW1[c], sA[c])) + d1;
        if (sc0 < best0){ best0=sc0; bl0=c; }
        if (sc1 < best1){ best1=sc1; bl1=c; }
      }
      int b0 = __builtin_amdgcn_readfirstlane(bl0);
      int b1 = __builtin_amdgcn_readfirstlane(bl1);

      {
        float* sb = s_sums + b0*DD + lane;  // physical p = j*256+m*64+lane
        #pragma unroll
        for (int j=0;j<3;j++)
          #pragma unroll
          for (int m=0;m<4;m++)
            atomicAdd(&sb[j*256 + m*64], ta[j].f[m]);
        if (lane==0){
          atomicAdd(&s_cnt[b0],1); atomicAdd(&s_sxg[b0],xg0); atomicAdd(&s_syg[b0],yg0);
        }
      }
      if (v1){
        float* sb = s_sums + b1*DD + lane;
        #pragma unroll
        for (int j=0;j<3;j++)
          #pragma unroll
          for (int m=0;m<4;m++)
            atomicAdd(&sb[j*256 + m*64], tb[j].f[m]);
        if (lane==0){
          atomicAdd(&s_cnt[b1],1); atomicAdd(&s_sxg[b1],xg1); atomicAdd(&s_syg[b1],yg1);
        }
      }
      if (i+2 < nt) stage(i+2);
    }
  }
  __syncthreads();

  float* fo = fsums + ((size_t)(k*GA+g))*CC*DD;
  for (int x=tid;x<CC*DD;x+=256) fo[x]=s_sums[x];
  if (tid<CC){
    size_t o = (size_t)(k*GA+g)*CC + tid;
    osxg[o]=s_sxg[tid]; osyg[o]=s_syg[tid]; ocnt[o]=s_cnt[tid];
  }
}

// ---------- 4. deterministic reduce over GA partials + centroid update ----------
// fsums physical p = j*256 + m*64 + l ; logical d = 256*j + 4*l + m
__global__ __launch_bounds__(256) void update_kernel(
  const float* __restrict__ fsums, const float* __restrict__ osxg, const float* __restrict__ osyg,
  const int* __restrict__ ocnt, const float* __restrict__ Wp, const float* __restrict__ bp,
  float* __restrict__ cent)
{
  int idx = blockIdx.x*256 + threadIdx.x;   // over K*C*D ; (k,c) uniform per block
  int d  = idx % DD;
  int kc = idx / DD;
  int k  = kc / CC, c = kc % CC;
  int j = d >> 8, r = d & 255, l = r >> 2, m = r & 3;
  int p = (j << 8) | (m << 6) | l;
  __shared__ float sX[GA], sY[GA]; __shared__ int sN[GA];
  if (threadIdx.x < GA){
    int g = threadIdx.x;
    size_t o = (size_t)(k*GA+g)*CC + c;
    sX[g]=osxg[o]; sY[g]=osyg[o]; sN[g]=ocnt[o];
  }
  __syncthreads();
  int n=0; float sx=0.f, sy=0.f;
  for (int t=0;t<GA;t++){ n+=sN[t]; sx+=sX[t]; sy+=sY[t]; }
  float s=0.f;
  for (int g=0; g<GA; g++)
    s += fsums[((size_t)(k*GA+g)*CC + c)*DD + p];
  if (n > 0){
    float nf = (float)n;
    float ts = s + sx*Wp[d] + sy*Wp[DD+d] + nf*bp[d];  // factored posenc re-applied
    cent[(size_t)kc*DD + d] = ts / nf;
  } // else keep old centroid
}

// ---------- 5. MLP ----------
__global__ __launch_bounds__(256) void mlp1_kernel(const float* __restrict__ cent,
  const float* __restrict__ W1, const float* __restrict__ b1, float* __restrict__ h1)
{
  int k = blockIdx.y; int col = blockIdx.x*256 + threadIdx.x;
  __shared__ float srow[CC*DD];
  for (int x=threadIdx.x; x<CC*DD; x+=256) srow[x] = cent[(size_t)k*CC*DD + x];
  __syncthreads();
  float acc[CC];
  #pragma unroll
  for (int r=0;r<CC;r++) acc[r]=0.f;
  for (int dd=0; dd<DD; dd++){
    float wv = W1[(size_t)dd*DD + col];
    #pragma unroll
    for (int r=0;r<CC;r++) acc[r] = fmaf(srow[r*DD+dd], wv, acc[r]);
  }
  float bb = b1[col];
  #pragma unroll
  for (int r=0;r<CC;r++){
    float x = acc[r] + bb;
    h1[((size_t)k*CC+r)*DD + col] = 0.5f*x*(1.f+erff(x*0.70710678118654752440f));
  }
}

__global__ __launch_bounds__(256) void mlp2_kernel(const float* __restrict__ h1,
  const float* __restrict__ W2, const float* __restrict__ b2, float* __restrict__ out)
{
  int k = blockIdx.y; int col = blockIdx.x*256 + threadIdx.x;
  __shared__ float srow[CC*DD];
  for (int x=threadIdx.x; x<CC*DD; x+=256) srow[x] = h1[(size_t)k*CC*DD + x];
  __syncthreads();
  float acc[CC];
  #pragma unroll
  for (int r=0;r<CC;r++) acc[r]=0.f;
  for (int dd=0; dd<DD; dd++){
    float wv = W2[(size_t)dd*DD + col];
    #pragma unroll
    for (int r=0;r<CC;r++) acc[r] = fmaf(srow[r*DD+dd], wv, acc[r]);
  }
  float bb2 = b2[col];
  #pragma unroll
  for (int r=0;r<CC;r++) out[((size_t)k*CC+r)*DD + col] = acc[r] + bb2;
}

// ---------- launch ----------
extern "C" void kernel_launch(void* const* d_in, const int* in_sizes, int n_in,
                              void* d_out, int out_size, void* d_ws, size_t ws_size,
                              hipStream_t stream)
{
  const float* feat = (const float*)d_in[0];
  const float* mask = (const float*)d_in[1];
  const float* boxes= (const float*)d_in[2];
  const float* Wp   = (const float*)d_in[3];
  const float* bp   = (const float*)d_in[4];
  const float* W1   = (const float*)d_in[5];
  const float* b1   = (const float*)d_in[6];
  const float* W2   = (const float*)d_in[7];
  const float* b2   = (const float*)d_in[8];
  const int*   iidx = (const int*)d_in[9];
  const int*   prawh= (const int*)d_in[10];
  const int*   praww= (const int*)d_in[11];
  float* out = (float*)d_out;

  auto align = [](size_t x){ return (x + 255) & ~(size_t)255; };
  size_t off = 0;
  size_t o_cent = off; off = align(off + (size_t)KIMG*CC*DD*4);
  size_t o_vidx = off; off = align(off + (size_t)KIMG*NTOK*4);
  size_t o_vcnt = off; off = align(off + (size_t)KIMG*4);
  size_t o_scal = off; off = align(off + (size_t)KIMG*CC*4*4);
  size_t o_h1   = off; off = align(off + (size_t)KIMG*CC*DD*4);
  size_t o_fs   = off; off = align(off + (size_t)KIMG*GA*CC*DD*4);
  size_t o_sx   = off; off = align(off + (size_t)KIMG*GA*CC*4);
  size_t o_sy   = off; off = align(off + (size_t)KIMG*GA*CC*4);
  size_t o_cn   = off; off = align(off + (size_t)KIMG*GA*CC*4);
  (void)ws_size;  // ~10.3 MB needed; prior rounds confirm ws_size >= 16.8 MB

  char* ws = (char*)d_ws;
  float* cent  = (float*)(ws + o_cent);
  int*   vidx  = (int*)  (ws + o_vidx);
  int*   vcnt  = (int*)  (ws + o_vcnt);
  float* scal  = (float*)(ws + o_scal);
  float* h1    = (float*)(ws + o_h1);
  float* fsums = (float*)(ws + o_fs);
  float* sxg   = (float*)(ws + o_sx);
  float* syg   = (float*)(ws + o_sy);
  int*   ocnt  = (int*)  (ws + o_cn);

  compact_kernel<<<KIMG,256,0,stream>>>(mask, vidx, vcnt);
  init_kernel<<<KIMG,256,0,stream>>>(feat, boxes, Wp, bp, iidx, prawh, praww, cent);
  scalar_kernel<<<dim3(CC,KIMG),64,0,stream>>>(cent, Wp, bp, scal);
  for (int it=0; it<NITER; ++it){
    assign_kernel<<<dim3(GA,KIMG),256,0,stream>>>(feat, boxes, prawh, praww,
        cent, scal, vidx, vcnt, fsums, sxg, syg, ocnt);
    update_kernel<<<(KIMG*CC*DD)/256,256,0,stream>>>(fsums, sxg, syg, ocnt, Wp, bp, cent);
    if (it < NITER-1)
      scalar_kernel<<<dim3(CC,KIMG),64,0,stream>>>(cent, Wp, bp, scal);
  }
  mlp1_kernel<<<dim3(3,KIMG),256,0,stream>>>(cent, W1, b1, h1);
  mlp2_kernel<<<dim3(3,KIMG),256,0,stream>>>(h1, W2, b2, out);
}